// Round 1
// baseline (116.501 us; speedup 1.0000x reference)
//
#include <hip/hip_runtime.h>

// ParallelRetention  B=4 S=4096 F=128  gamma=0.96875
// R3: everything MFMA. prep tiles W into B-fragment order (WbF); proj is a
//     bf16 MFMA GEMM emitting fragment-ordered QbF/VtF + row-major Kb;
//     retention: s-tile 32, chunk 64, 2 blocks/CU, coalesced frag loads.
// Window: gamma^512 ~ 8.7e-8 -> t-window 512 exact to ~1e-6.

#define S_LEN 4096
#define B_N   4
#define F_N   128
#define WIN   512
#define LOG2_GAMMA (-0.0458036905705339f)

typedef unsigned short u16;
typedef unsigned int   u32;
typedef __attribute__((ext_vector_type(8))) short bf16x8;   // 8 bf16 (4 VGPRs)
typedef __attribute__((ext_vector_type(4))) float f32x4;

__device__ inline u16 f2bf(float x) {
    u32 u = __builtin_bit_cast(u32, x);
    u32 r = (u + 0x7fffu + ((u >> 16) & 1u)) >> 16;
    return (u16)r;
}

__device__ inline uint4 pack8(const u16* p) {
    uint4 v;
    v.x = (u32)p[0] | ((u32)p[1] << 16);
    v.y = (u32)p[2] | ((u32)p[3] << 16);
    v.z = (u32)p[4] | ((u32)p[5] << 16);
    v.w = (u32)p[6] | ((u32)p[7] << 16);
    return v;
}

// ---------------------------------------------------------------------------
// prep: W[3][128][128] fp32 -> WbF bf16 fragment order.
// WbF[fragid][lane*8+j] = W[mat][nt*16+(lane&15)][ks*32+(lane>>4)*8+j],
// fragid = mat*32 + nt*4 + ks.  grid 24 x 256.
__global__ void prep_kernel(const float* __restrict__ Wq,
                            const float* __restrict__ Wk,
                            const float* __restrict__ Wv,
                            u16* __restrict__ WbF)
{
    const int idx    = blockIdx.x * 256 + threadIdx.x;   // 0..6143
    const int lane   = idx & 63;
    const int fragid = idx >> 6;                         // 0..95
    const int ks     = fragid & 3;
    const int nt     = (fragid >> 2) & 7;
    const int mat    = fragid >> 5;
    const float* W = (mat == 0) ? Wq : (mat == 1 ? Wk : Wv);
    const float* src = W + (nt * 16 + (lane & 15)) * F_N + ks * 32 + (lane >> 4) * 8;
    float4 a = *(const float4*)src;
    float4 b = *(const float4*)(src + 4);
    u16 o[8] = {f2bf(a.x), f2bf(a.y), f2bf(a.z), f2bf(a.w),
                f2bf(b.x), f2bf(b.y), f2bf(b.z), f2bf(b.w)};
    *(uint4*)(WbF + fragid * 512 + lane * 8) = pack8(o);
}

// ---------------------------------------------------------------------------
// proj: grid 512 x 256 (4 waves). Block = 32 rows. wave w: m-tile mt=w&1,
// n-half nh=w>>1 (4 n-tiles). Outputs:
//   QbF[b][g=s>>4][ks0..7][lane*8]  (A-frag order, k=256)
//   Kb [b*4096+s][256]              (row-major, for LDS staging)
//   VtF[b][tb=s>>5][ft0..7][lane*8] (B-frag order, k=t)
__global__ __launch_bounds__(256, 2)
void proj_kernel(const float* __restrict__ x, const u16* __restrict__ WbF,
                 const float* __restrict__ bq, const float* __restrict__ bk,
                 const float* __restrict__ bv, const float* __restrict__ theta,
                 u16* __restrict__ QbF, u16* __restrict__ Kb,
                 u16* __restrict__ VtF)
{
    __shared__ __align__(16) u16 xb[32 * 136];     // [row][128+8]
    __shared__ __align__(16) u16 obuf[32 * 264];   // q/k: [32][256+8]; v: [128][40]

    const int tid  = threadIdx.x;
    const int lane = tid & 63;
    const int w    = __builtin_amdgcn_readfirstlane(tid >> 6);
    const int r0   = blockIdx.x * 32;
    const int b    = r0 >> 12;
    const int s0   = r0 & (S_LEN - 1);
    const int col  = lane & 15;
    const int quad = lane >> 4;
    const int mt   = w & 1;
    const int nh   = w >> 1;

    // ---- stage x (fp32 -> bf16) ----
#pragma unroll
    for (int it = 0; it < 4; ++it) {
        const int c   = it * 256 + tid;      // 0..1023
        const int row = c >> 5;
        const int k0  = (c & 31) * 4;
        float4 v = *(const float4*)(x + (r0 + row) * F_N + k0);
        u16 o[4] = {f2bf(v.x), f2bf(v.y), f2bf(v.z), f2bf(v.w)};
        *(uint2*)(xb + row * 136 + k0) =
            make_uint2((u32)o[0] | ((u32)o[1] << 16), (u32)o[2] | ((u32)o[3] << 16));
    }
    __syncthreads();

    // ---- A-frags ----
    bf16x8 af[4];
#pragma unroll
    for (int ks = 0; ks < 4; ++ks)
        af[ks] = *(const bf16x8*)(xb + (mt * 16 + col) * 136 + ks * 32 + quad * 8);

    // ---- MFMA: q, k, v ----
    f32x4 qa[4], ka[4], va[4];
#pragma unroll
    for (int nt = 0; nt < 4; ++nt) {
        qa[nt] = (f32x4){0.f, 0.f, 0.f, 0.f};
        ka[nt] = (f32x4){0.f, 0.f, 0.f, 0.f};
        va[nt] = (f32x4){0.f, 0.f, 0.f, 0.f};
    }
#pragma unroll
    for (int nt = 0; nt < 4; ++nt) {
        const int ng = nh * 4 + nt;
#pragma unroll
        for (int ks = 0; ks < 4; ++ks) {
            bf16x8 bqf = *(const bf16x8*)(WbF + ((0 * 8 + ng) * 4 + ks) * 512 + lane * 8);
            bf16x8 bkf = *(const bf16x8*)(WbF + ((1 * 8 + ng) * 4 + ks) * 512 + lane * 8);
            bf16x8 bvf = *(const bf16x8*)(WbF + ((2 * 8 + ng) * 4 + ks) * 512 + lane * 8);
            qa[nt] = __builtin_amdgcn_mfma_f32_16x16x32_bf16(af[ks], bqf, qa[nt], 0, 0, 0);
            ka[nt] = __builtin_amdgcn_mfma_f32_16x16x32_bf16(af[ks], bkf, ka[nt], 0, 0, 0);
            va[nt] = __builtin_amdgcn_mfma_f32_16x16x32_bf16(af[ks], bvf, va[nt], 0, 0, 0);
        }
    }

    // ---- per-lane bias/theta ----
    float bqv[4], bkv[4], bvv[4], thv[4];
#pragma unroll
    for (int nt = 0; nt < 4; ++nt) {
        const int o = nh * 64 + nt * 16 + col;
        bqv[nt] = bq[o]; bkv[nt] = bk[o]; bvv[nt] = bv[o]; thv[nt] = theta[o];
    }
    float cs[16], sn[16];
#pragma unroll
    for (int nt = 0; nt < 4; ++nt)
#pragma unroll
        for (int r = 0; r < 4; ++r) {
            const int srow = s0 + mt * 16 + quad * 4 + r;
            __sincosf((float)(srow + 1) * thv[nt], &sn[nt * 4 + r], &cs[nt * 4 + r]);
        }

    // ---- Q' -> obuf -> QbF ----
#pragma unroll
    for (int nt = 0; nt < 4; ++nt)
#pragma unroll
        for (int r = 0; r < 4; ++r) {
            const float q = qa[nt][r] + bqv[nt];
            const int row = mt * 16 + quad * 4 + r;
            const int o   = nh * 64 + nt * 16 + col;
            obuf[row * 264 + o]       = f2bf(q * cs[nt * 4 + r]);
            obuf[row * 264 + 128 + o] = f2bf(q * sn[nt * 4 + r]);
        }
    __syncthreads();
#pragma unroll
    for (int it = 0; it < 4; ++it) {
        const int c  = it * 256 + tid;           // 0..1023
        const int gl = c >> 9;                   // 0..1
        const int ks = (c >> 6) & 7;
        const int ln = c & 63;
        uint4 v = *(const uint4*)(obuf + (gl * 16 + (ln & 15)) * 264 +
                                  ks * 32 + (ln >> 4) * 8);
        *(uint4*)(QbF + (((b * 256 + (s0 >> 4) + gl) * 8 + ks) * 512) + ln * 8) = v;
    }
    __syncthreads();

    // ---- K' -> obuf -> Kb (row-major) ----
#pragma unroll
    for (int nt = 0; nt < 4; ++nt)
#pragma unroll
        for (int r = 0; r < 4; ++r) {
            const float k = ka[nt][r] + bkv[nt];
            const int row = mt * 16 + quad * 4 + r;
            const int o   = nh * 64 + nt * 16 + col;
            obuf[row * 264 + o]       = f2bf(k * cs[nt * 4 + r]);
            obuf[row * 264 + 128 + o] = f2bf(k * sn[nt * 4 + r]);
        }
    __syncthreads();
#pragma unroll
    for (int it = 0; it < 4; ++it) {
        const int c   = it * 256 + tid;
        const int row = c >> 5;
        const int k0  = (c & 31) * 8;
        uint4 v = *(const uint4*)(obuf + row * 264 + k0);
        *(uint4*)(Kb + (r0 + row) * 256 + k0) = v;
    }
    __syncthreads();

    // ---- V -> obuf[f][40] -> VtF ----
#pragma unroll
    for (int nt = 0; nt < 4; ++nt)
#pragma unroll
        for (int r = 0; r < 4; ++r) {
            const float vv = va[nt][r] + bvv[nt];
            const int f  = nh * 64 + nt * 16 + col;
            const int sl = mt * 16 + quad * 4 + r;
            obuf[f * 40 + sl] = f2bf(vv);
        }
    __syncthreads();
#pragma unroll
    for (int it = 0; it < 2; ++it) {
        const int c  = it * 256 + tid;           // 0..511
        const int ft = c >> 6;                   // 0..7
        const int ln = c & 63;
        uint4 v = *(const uint4*)(obuf + (ft * 16 + (ln & 15)) * 40 + (ln >> 4) * 8);
        *(uint4*)(VtF + ((b * 128 + (s0 >> 5)) * 8 + ft) * 512 + ln * 8) = v;
    }
}

// ---------------------------------------------------------------------------
// retention: grid (128, 4) x 256 (4 waves). s-tile 32, t-chunk 64.
// wave w: ssub=(w&1)*16; P: tt=(w>>1)*2+{0,1}; PV: f-half fh=w>>1.
__global__ __launch_bounds__(256, 2)
void retention_kernel(const u16* __restrict__ QbF, const u16* __restrict__ Kb,
                      const u16* __restrict__ VtF, float* __restrict__ out)
{
    __shared__ __align__(16) u16 K_lds[64 * 264];   // [t][256+8]
    __shared__ __align__(16) u16 P_lds[32 * 136];   // [s][128+8]

    const int tid  = threadIdx.x;
    const int lane = tid & 63;
    const int w    = __builtin_amdgcn_readfirstlane(tid >> 6);
    const int b    = blockIdx.y;
    const int s0   = blockIdx.x * 32;
    const int col  = lane & 15;
    const int quad = lane >> 4;
    const int ssub = (w & 1) * 16;
    const int fh   = w >> 1;

    const int t_start = (s0 >= WIN) ? ((s0 - WIN) & ~63) : 0;
    const int nch     = (s0 + 32 - t_start + 63) >> 6;

    const u16* Kbb = Kb + (b << 12) * 256;

    // Q A-frags (coalesced, fragment-ordered)
    const int g = ((s0 + ssub) >> 4);
    bf16x8 qf[8];
#pragma unroll
    for (int ks = 0; ks < 8; ++ks)
        qf[ks] = *(const bf16x8*)(QbF + ((b * 256 + g) * 8 + ks) * 512 + lane * 8);

    f32x4 oacc[4];
#pragma unroll
    for (int ft = 0; ft < 4; ++ft) oacc[ft] = (f32x4){0.f, 0.f, 0.f, 0.f};

    for (int ch = 0; ch < nch; ++ch) {
        const int tc = t_start + (ch << 6);
        // ---- stage K chunk [64 t][256 k] ----
#pragma unroll
        for (int i = 0; i < 8; ++i) {
            const int c  = i * 256 + tid;
            const int t  = c >> 5;
            const int k0 = (c & 31) * 8;
            int trow = tc + t; if (trow > S_LEN - 1) trow = S_LEN - 1;
            uint4 v = *(const uint4*)(Kbb + trow * 256 + k0);
            *(uint4*)(K_lds + t * 264 + k0) = v;
        }
        __syncthreads();

        // ---- P = Q'K'^T + decay -> P_lds ----
#pragma unroll
        for (int tp = 0; tp < 2; ++tp) {
            const int tt = fh * 2 + tp;
            f32x4 acc = (f32x4){0.f, 0.f, 0.f, 0.f};
#pragma unroll
            for (int ks = 0; ks < 8; ++ks) {
                bf16x8 bfr = *(const bf16x8*)(K_lds + (tt * 16 + col) * 264 +
                                              ks * 32 + quad * 8);
                acc = __builtin_amdgcn_mfma_f32_16x16x32_bf16(qf[ks], bfr, acc, 0, 0, 0);
            }
            const int tglob = tc + tt * 16 + col;
#pragma unroll
            for (int r = 0; r < 4; ++r) {
                const int sglob = s0 + ssub + quad * 4 + r;
                const int e = sglob - tglob;
                const float d = (e >= 0) ? exp2f((float)e * LOG2_GAMMA) : 0.f;
                P_lds[(ssub + quad * 4 + r) * 136 + tt * 16 + col] = f2bf(acc[r] * d);
            }
        }
        __syncthreads();

        // ---- O += P V  (V B-frags coalesced from VtF) ----
        bf16x8 pa[2];
#pragma unroll
        for (int ks = 0; ks < 2; ++ks)
            pa[ks] = *(const bf16x8*)(P_lds + (ssub + col) * 136 + ks * 32 + quad * 8);
#pragma unroll
        for (int ks = 0; ks < 2; ++ks) {
            int tb = (tc >> 5) + ks; if (tb > 127) tb = 127;   // decay zeroed
#pragma unroll
            for (int ft = 0; ft < 4; ++ft) {
                const int ftg = fh * 4 + ft;
                bf16x8 vb = *(const bf16x8*)(VtF + ((b * 128 + tb) * 8 + ftg) * 512 +
                                             lane * 8);
                oacc[ft] = __builtin_amdgcn_mfma_f32_16x16x32_bf16(pa[ks], vb,
                                                                   oacc[ft], 0, 0, 0);
            }
        }
        // next iteration's staging write to K_lds is safe: all waves passed
        // the P->PV barrier (K reads done); P_lds overwrite is gated by the
        // post-staging barrier.
    }

    float* ob = out + ((b << 12) + s0) * F_N;
#pragma unroll
    for (int ft = 0; ft < 4; ++ft)
#pragma unroll
        for (int r = 0; r < 4; ++r)
            ob[(ssub + quad * 4 + r) * F_N + fh * 64 + ft * 16 + col] = oacc[ft][r];
}

// ---------------------------------------------------------------------------
extern "C" void kernel_launch(void* const* d_in, const int* in_sizes, int n_in,
                              void* d_out, int out_size, void* d_ws, size_t ws_size,
                              hipStream_t stream) {
    const float* x     = (const float*)d_in[0];
    const float* Wq    = (const float*)d_in[1];
    const float* bq    = (const float*)d_in[2];
    const float* Wk    = (const float*)d_in[3];
    const float* bk    = (const float*)d_in[4];
    const float* Wv    = (const float*)d_in[5];
    const float* bv    = (const float*)d_in[6];
    const float* theta = (const float*)d_in[7];
    float* out = (float*)d_out;

    u16* ws  = (u16*)d_ws;
    u16* QbF = ws;                       // 4,194,304 u16 (8 MiB)
    u16* Kb  = ws + 4194304;             // 4,194,304 u16
    u16* VtF = ws + 8388608;             // 2,097,152 u16
    u16* WbF = ws + 10485760;            // 49,152 u16

    prep_kernel<<<24, 256, 0, stream>>>(Wq, Wk, Wv, WbF);
    proj_kernel<<<512, 256, 0, stream>>>(x, WbF, bq, bk, bv, theta, QbF, Kb, VtF);
    retention_kernel<<<dim3(128, B_N), 256, 0, stream>>>(QbF, Kb, VtF, out);
}

// Round 2
// 105.250 us; speedup vs baseline: 1.1069x; 1.1069x over previous
//
#include <hip/hip_runtime.h>

// ParallelRetention  B=4 S=4096 F=128  gamma=0.96875
// R4: retention K staged via global_load_lds (width 16) into a double buffer
//     with counted vmcnt(16) + raw s_barrier (stage of chunk+1 in flight
//     across P+PV of chunk); Kb stored pre-swizzled (16B-block ^= row&7) so
//     the linear gload_lds dest + swizzled ds_read is conflict-free;
//     VtF fragments prefetched at loop top; XCD-aware s-block swizzle.
//     proj: merged Q'/K' LDS phases (4 barriers).
// Window: gamma^512 ~ 8.7e-8 -> t-window 512 exact to ~1e-6.

#define S_LEN 4096
#define B_N   4
#define F_N   128
#define WIN   512
#define LOG2_GAMMA (-0.0458036905705339f)

typedef unsigned short u16;
typedef unsigned int   u32;
typedef __attribute__((ext_vector_type(8))) short bf16x8;   // 8 bf16 (4 VGPRs)
typedef __attribute__((ext_vector_type(4))) float f32x4;

__device__ inline u16 f2bf(float x) {
    u32 u = __builtin_bit_cast(u32, x);
    u32 r = (u + 0x7fffu + ((u >> 16) & 1u)) >> 16;
    return (u16)r;
}

__device__ inline uint4 pack8(const u16* p) {
    uint4 v;
    v.x = (u32)p[0] | ((u32)p[1] << 16);
    v.y = (u32)p[2] | ((u32)p[3] << 16);
    v.z = (u32)p[4] | ((u32)p[5] << 16);
    v.w = (u32)p[6] | ((u32)p[7] << 16);
    return v;
}

// ---------------------------------------------------------------------------
// prep: W[3][128][128] fp32 -> WbF bf16 fragment order.
__global__ void prep_kernel(const float* __restrict__ Wq,
                            const float* __restrict__ Wk,
                            const float* __restrict__ Wv,
                            u16* __restrict__ WbF)
{
    const int idx    = blockIdx.x * 256 + threadIdx.x;   // 0..6143
    const int lane   = idx & 63;
    const int fragid = idx >> 6;                         // 0..95
    const int ks     = fragid & 3;
    const int nt     = (fragid >> 2) & 7;
    const int mat    = fragid >> 5;
    const float* W = (mat == 0) ? Wq : (mat == 1 ? Wk : Wv);
    const float* src = W + (nt * 16 + (lane & 15)) * F_N + ks * 32 + (lane >> 4) * 8;
    float4 a = *(const float4*)src;
    float4 b = *(const float4*)(src + 4);
    u16 o[8] = {f2bf(a.x), f2bf(a.y), f2bf(a.z), f2bf(a.w),
                f2bf(b.x), f2bf(b.y), f2bf(b.z), f2bf(b.w)};
    *(uint4*)(WbF + fragid * 512 + lane * 8) = pack8(o);
}

// ---------------------------------------------------------------------------
// proj: grid 512 x 256 (4 waves). Block = 32 rows.
// Outputs: QbF (A-frag order), Kb (row-major, 16B blocks pre-swizzled with
// blk ^= row&7 for retention's global_load_lds path), VtF (B-frag order).
__global__ __launch_bounds__(256, 2)
void proj_kernel(const float* __restrict__ x, const u16* __restrict__ WbF,
                 const float* __restrict__ bq, const float* __restrict__ bk,
                 const float* __restrict__ bv, const float* __restrict__ theta,
                 u16* __restrict__ QbF, u16* __restrict__ Kb,
                 u16* __restrict__ VtF)
{
    __shared__ __align__(16) u16 xb[32 * 136];      // [row][128+8]
    __shared__ __align__(16) u16 obufQ[32 * 264];   // Q': [32][256+8]; later V: [128][40]
    __shared__ __align__(16) u16 obufK[32 * 264];   // K': [32][256+8]

    const int tid  = threadIdx.x;
    const int lane = tid & 63;
    const int w    = __builtin_amdgcn_readfirstlane(tid >> 6);
    const int r0   = blockIdx.x * 32;
    const int b    = r0 >> 12;
    const int s0   = r0 & (S_LEN - 1);
    const int col  = lane & 15;
    const int quad = lane >> 4;
    const int mt   = w & 1;
    const int nh   = w >> 1;

    // ---- stage x (fp32 -> bf16) ----
#pragma unroll
    for (int it = 0; it < 4; ++it) {
        const int c   = it * 256 + tid;      // 0..1023
        const int row = c >> 5;
        const int k0  = (c & 31) * 4;
        float4 v = *(const float4*)(x + (r0 + row) * F_N + k0);
        u16 o[4] = {f2bf(v.x), f2bf(v.y), f2bf(v.z), f2bf(v.w)};
        *(uint2*)(xb + row * 136 + k0) =
            make_uint2((u32)o[0] | ((u32)o[1] << 16), (u32)o[2] | ((u32)o[3] << 16));
    }
    __syncthreads();

    // ---- A-frags ----
    bf16x8 af[4];
#pragma unroll
    for (int ks = 0; ks < 4; ++ks)
        af[ks] = *(const bf16x8*)(xb + (mt * 16 + col) * 136 + ks * 32 + quad * 8);

    // ---- MFMA: q, k, v ----
    f32x4 qa[4], ka[4], va[4];
#pragma unroll
    for (int nt = 0; nt < 4; ++nt) {
        qa[nt] = (f32x4){0.f, 0.f, 0.f, 0.f};
        ka[nt] = (f32x4){0.f, 0.f, 0.f, 0.f};
        va[nt] = (f32x4){0.f, 0.f, 0.f, 0.f};
    }
#pragma unroll
    for (int nt = 0; nt < 4; ++nt) {
        const int ng = nh * 4 + nt;
#pragma unroll
        for (int ks = 0; ks < 4; ++ks) {
            bf16x8 bqf = *(const bf16x8*)(WbF + ((0 * 8 + ng) * 4 + ks) * 512 + lane * 8);
            bf16x8 bkf = *(const bf16x8*)(WbF + ((1 * 8 + ng) * 4 + ks) * 512 + lane * 8);
            bf16x8 bvf = *(const bf16x8*)(WbF + ((2 * 8 + ng) * 4 + ks) * 512 + lane * 8);
            qa[nt] = __builtin_amdgcn_mfma_f32_16x16x32_bf16(af[ks], bqf, qa[nt], 0, 0, 0);
            ka[nt] = __builtin_amdgcn_mfma_f32_16x16x32_bf16(af[ks], bkf, ka[nt], 0, 0, 0);
            va[nt] = __builtin_amdgcn_mfma_f32_16x16x32_bf16(af[ks], bvf, va[nt], 0, 0, 0);
        }
    }

    // ---- per-lane bias/theta ----
    float bqv[4], bkv[4], bvv[4], thv[4];
#pragma unroll
    for (int nt = 0; nt < 4; ++nt) {
        const int o = nh * 64 + nt * 16 + col;
        bqv[nt] = bq[o]; bkv[nt] = bk[o]; bvv[nt] = bv[o]; thv[nt] = theta[o];
    }
    float cs[16], sn[16];
#pragma unroll
    for (int nt = 0; nt < 4; ++nt)
#pragma unroll
        for (int r = 0; r < 4; ++r) {
            const int srow = s0 + mt * 16 + quad * 4 + r;
            __sincosf((float)(srow + 1) * thv[nt], &sn[nt * 4 + r], &cs[nt * 4 + r]);
        }

    // ---- Q' -> obufQ, K' -> obufK (single barrier) ----
#pragma unroll
    for (int nt = 0; nt < 4; ++nt)
#pragma unroll
        for (int r = 0; r < 4; ++r) {
            const float q = qa[nt][r] + bqv[nt];
            const float k = ka[nt][r] + bkv[nt];
            const int row = mt * 16 + quad * 4 + r;
            const int o   = nh * 64 + nt * 16 + col;
            const float c = cs[nt * 4 + r], s = sn[nt * 4 + r];
            obufQ[row * 264 + o]       = f2bf(q * c);
            obufQ[row * 264 + 128 + o] = f2bf(q * s);
            obufK[row * 264 + o]       = f2bf(k * c);
            obufK[row * 264 + 128 + o] = f2bf(k * s);
        }
    __syncthreads();

    // ---- copy out QbF (A-frag order) ----
#pragma unroll
    for (int it = 0; it < 4; ++it) {
        const int c  = it * 256 + tid;           // 0..1023
        const int gl = c >> 9;                   // 0..1
        const int ks = (c >> 6) & 7;
        const int ln = c & 63;
        uint4 v = *(const uint4*)(obufQ + (gl * 16 + (ln & 15)) * 264 +
                                  ks * 32 + (ln >> 4) * 8);
        *(uint4*)(QbF + (((b * 256 + (s0 >> 4) + gl) * 8 + ks) * 512) + ln * 8) = v;
    }
    // ---- copy out Kb (row-major, 16B blocks swizzled: blk ^= row&7) ----
#pragma unroll
    for (int it = 0; it < 4; ++it) {
        const int c   = it * 256 + tid;
        const int row = c >> 5;
        const int k4  = c & 31;
        uint4 v = *(const uint4*)(obufK + row * 264 + k4 * 8);
        *(uint4*)(Kb + (r0 + row) * 256 + ((k4 ^ (row & 7)) * 8)) = v;
    }
    __syncthreads();   // obufQ about to be reused for V

    // ---- V -> obufQ[f][40] -> VtF ----
#pragma unroll
    for (int nt = 0; nt < 4; ++nt)
#pragma unroll
        for (int r = 0; r < 4; ++r) {
            const float vv = va[nt][r] + bvv[nt];
            const int f  = nh * 64 + nt * 16 + col;
            const int sl = mt * 16 + quad * 4 + r;
            obufQ[f * 40 + sl] = f2bf(vv);
        }
    __syncthreads();
#pragma unroll
    for (int it = 0; it < 2; ++it) {
        const int c  = it * 256 + tid;           // 0..511
        const int ft = c >> 6;                   // 0..7
        const int ln = c & 63;
        uint4 v = *(const uint4*)(obufQ + (ft * 16 + (ln & 15)) * 40 + (ln >> 4) * 8);
        *(uint4*)(VtF + ((b * 128 + (s0 >> 5)) * 8 + ft) * 512 + ln * 8) = v;
    }
}

// ---------------------------------------------------------------------------
// retention: grid (128, 4) x 256 (4 waves). s-tile 32, t-chunk 64.
// K double-buffered via global_load_lds; counted vmcnt; VtF prefetch;
// XCD-aware s-block swizzle (128 blocks = 8 XCDs x 16 consecutive).
__global__ __launch_bounds__(256, 2)
void retention_kernel(const u16* __restrict__ QbF, const u16* __restrict__ Kb,
                      const u16* __restrict__ VtF, float* __restrict__ out)
{
    __shared__ __align__(16) u16 K_lds[2 * 64 * 256];   // 2 x [t][256] linear, 64 KiB
    __shared__ __align__(16) u16 P_lds[32 * 136];       // [s][128+8]

    const int tid  = threadIdx.x;
    const int lane = tid & 63;
    const int w    = __builtin_amdgcn_readfirstlane(tid >> 6);
    const int b    = blockIdx.y;
    const int bx   = blockIdx.x;                        // 0..127
    const int sblk = ((bx & 7) << 4) + (bx >> 3);       // XCD swizzle (bijective)
    const int s0   = sblk * 32;
    const int col  = lane & 15;
    const int quad = lane >> 4;
    const int ssub = (w & 1) * 16;
    const int fh   = w >> 1;

    const int t_start = (s0 >= WIN) ? ((s0 - WIN) & ~63) : 0;
    const int nch     = (s0 + 32 - t_start + 63) >> 6;

    const char* KbbC = (const char*)(Kb + (b << 12) * 256);

    // Q A-frags (coalesced, fragment-ordered)
    const int g = ((s0 + ssub) >> 4);
    bf16x8 qf[8];
#pragma unroll
    for (int ks = 0; ks < 8; ++ks)
        qf[ks] = *(const bf16x8*)(QbF + ((b * 256 + g) * 8 + ks) * 512 + lane * 8);

    f32x4 oacc[4];
#pragma unroll
    for (int ft = 0; ft < 4; ++ft) oacc[ft] = (f32x4){0.f, 0.f, 0.f, 0.f};

    // ---- stage one chunk into K_lds[buf] via global_load_lds (8 instrs/wave)
    // LDS layout is linear [row][256]; Kb is pre-swizzled so the swizzled
    // ds_read below recovers K'[t][j]. Clamped rows land in t>s region (decay 0).
    auto stage = [&](int tcs, int buf) {
#pragma unroll
        for (int i = 0; i < 8; ++i) {
            const int m   = i * 4 + w;               // 0..31 (wave-interleaved)
            const int row = m * 2 + (lane >> 5);
            int trow = tcs + row; if (trow > S_LEN - 1) trow = S_LEN - 1;
            const char* gp = KbbC + trow * 512 + (lane & 31) * 16;
            char* lp = (char*)K_lds + buf * 32768 + m * 1024;   // wave-uniform
            __builtin_amdgcn_global_load_lds(
                (const __attribute__((address_space(1))) u32*)gp,
                (__attribute__((address_space(3))) u32*)lp, 16, 0, 0);
        }
    };

    stage(t_start, 0);

    for (int ch = 0; ch < nch; ++ch) {
        const int tc  = t_start + (ch << 6);
        const int cur = ch & 1;

        // ---- prefetch V B-frags for this chunk (issued before next stage so
        //      the compiler's wait for them is vmcnt(8), keeping stage in flight)
        bf16x8 vbr[8];
#pragma unroll
        for (int ks = 0; ks < 2; ++ks) {
            int tb = (tc >> 5) + ks; if (tb > 127) tb = 127;
#pragma unroll
            for (int ft = 0; ft < 4; ++ft)
                vbr[ks * 4 + ft] = *(const bf16x8*)(VtF +
                    ((b * 128 + tb) * 8 + fh * 4 + ft) * 512 + lane * 8);
        }

        // ---- issue stage of chunk+1 (always; last one is redundant/clamped)
        stage(tc + 64, cur ^ 1);

        // oldest 8 outstanding = this chunk's stage -> drain exactly those
        asm volatile("s_waitcnt vmcnt(16)" ::: "memory");
        __builtin_amdgcn_s_barrier();

        // ---- P = Q'K'^T + decay -> P_lds ----
#pragma unroll
        for (int tp = 0; tp < 2; ++tp) {
            const int tt = fh * 2 + tp;
            const int t  = tt * 16 + col;
            f32x4 acc = (f32x4){0.f, 0.f, 0.f, 0.f};
#pragma unroll
            for (int ks = 0; ks < 8; ++ks) {
                const int blk = (ks * 4 + quad) ^ (col & 7);   // t&7 == col&7
                bf16x8 bfr = *(const bf16x8*)(K_lds + cur * 16384 + t * 256 + blk * 8);
                acc = __builtin_amdgcn_mfma_f32_16x16x32_bf16(qf[ks], bfr, acc, 0, 0, 0);
            }
            const int tglob = tc + t;
#pragma unroll
            for (int r = 0; r < 4; ++r) {
                const int sglob = s0 + ssub + quad * 4 + r;
                const int e = sglob - tglob;
                const float d = (e >= 0) ? exp2f((float)e * LOG2_GAMMA) : 0.f;
                P_lds[(ssub + quad * 4 + r) * 136 + tt * 16 + col] = f2bf(acc[r] * d);
            }
        }
        asm volatile("s_waitcnt lgkmcnt(0)" ::: "memory");
        __builtin_amdgcn_s_barrier();

        // ---- O += P V  (V frags already in registers) ----
        bf16x8 pa[2];
#pragma unroll
        for (int ks = 0; ks < 2; ++ks)
            pa[ks] = *(const bf16x8*)(P_lds + (ssub + col) * 136 + ks * 32 + quad * 8);
#pragma unroll
        for (int ks = 0; ks < 2; ++ks)
#pragma unroll
            for (int ft = 0; ft < 4; ++ft)
                oacc[ft] = __builtin_amdgcn_mfma_f32_16x16x32_bf16(pa[ks],
                                vbr[ks * 4 + ft], oacc[ft], 0, 0, 0);
        // K_lds[cur^1] overwrite next iter is safe: this iter's post-P barrier
        // guarantees all waves' K ds_reads (lgkm) drained; P_lds overwrite is
        // gated by next iter's post-stage barrier (pa consumed by MFMA before it).
    }

    float* ob = out + ((b << 12) + s0) * F_N;
#pragma unroll
    for (int ft = 0; ft < 4; ++ft)
#pragma unroll
        for (int r = 0; r < 4; ++r)
            ob[(ssub + quad * 4 + r) * F_N + fh * 64 + ft * 16 + col] = oacc[ft][r];
}

// ---------------------------------------------------------------------------
extern "C" void kernel_launch(void* const* d_in, const int* in_sizes, int n_in,
                              void* d_out, int out_size, void* d_ws, size_t ws_size,
                              hipStream_t stream) {
    const float* x     = (const float*)d_in[0];
    const float* Wq    = (const float*)d_in[1];
    const float* bq    = (const float*)d_in[2];
    const float* Wk    = (const float*)d_in[3];
    const float* bk    = (const float*)d_in[4];
    const float* Wv    = (const float*)d_in[5];
    const float* bv    = (const float*)d_in[6];
    const float* theta = (const float*)d_in[7];
    float* out = (float*)d_out;

    u16* ws  = (u16*)d_ws;
    u16* QbF = ws;                       // 4,194,304 u16 (8 MiB)
    u16* Kb  = ws + 4194304;             // 4,194,304 u16
    u16* VtF = ws + 8388608;             // 2,097,152 u16
    u16* WbF = ws + 10485760;            // 49,152 u16

    prep_kernel<<<24, 256, 0, stream>>>(Wq, Wk, Wv, WbF);
    proj_kernel<<<512, 256, 0, stream>>>(x, WbF, bq, bk, bv, theta, QbF, Kb, VtF);
    retention_kernel<<<dim3(128, B_N), 256, 0, stream>>>(QbF, Kb, VtF, out);
}